// Round 1
// baseline (8087.003 us; speedup 1.0000x reference)
//
#include <hip/hip_runtime.h>

// ---------------- problem constants ----------------
constexpr int M_LZ = 96;           // Lanczos steps

// CSR capacity per matrix (expected nnz * ~1.25)
constexpr int CAP_L0 = 26240, CAP_L1 = 118016, CAP_L2 = 52480, CAP_B1 = 39360, CAP_B2 = 78720;
constexpr int CB_L0 = 0;
constexpr int CB_L1D = CB_L0 + CAP_L0;
constexpr int CB_L1U = CB_L1D + CAP_L1;
constexpr int CB_L2  = CB_L1U + CAP_L1;
constexpr int CB_B1  = CB_L2 + CAP_L2;
constexpr int CB_B2  = CB_B1 + CAP_B1;
constexpr int CAP_TOT= CB_B2 + CAP_B2;   // 432832

// rowptr offsets (ints) within W_PTR region
constexpr int P_L0=0, P_L1D=1025, P_L1U=4098, P_L2=7171, P_B1=9220, P_B2=10245;
// row-count offsets within W_CNT region
constexpr int C_L0=0, C_L1D=1024, C_L1U=4096, C_L2=7168, C_B1=9216, C_B2=10240;

// workspace layout (units: 4-byte words)
constexpr size_t W_CNT = 0;                         // 13312 ints
constexpr size_t W_PTR = 13312;                     // 13320 ints
constexpr size_t W_CIDX= W_PTR + 13320;             // CAP_TOT ints
constexpr size_t W_VAL = W_CIDX + CAP_TOT;          // CAP_TOT floats
constexpr size_t W_V   = W_VAL + CAP_TOT;           // 3 slots * 6144 (lanczos vectors)
constexpr size_t W_ACC = W_V + 3*6144;              // M_LZ*12 (per-step dot accumulators)
constexpr size_t W_TA  = W_ACC + (size_t)M_LZ*12;   // 3*M_LZ (tridiag alpha)
constexpr size_t W_TB  = W_TA + 3*M_LZ;             // 3*M_LZ (tridiag beta)
constexpr size_t W_EPS = W_TB + 3*M_LZ;             // 4
constexpr size_t W_UV  = W_EPS + 4;                 // 4*3072 (U_d,V_d,U_u,V_u)
constexpr size_t HBUF  = (size_t)6144*128;
constexpr size_t W_H   = W_UV + 4*3072;             // 2 ping-pong harmonic buffers
constexpr size_t W_SCAT= W_H + 2*HBUF;
constexpr size_t S0_OFF= 0;                          // 1024 x 384
constexpr size_t S1_OFF= (size_t)1024*384;           // 3072 x 640
constexpr size_t S2_OFF= S1_OFF + (size_t)3072*640;  // 2048 x 384
constexpr size_t SCAT_TOT = S2_OFF + (size_t)2048*384;
constexpr size_t W_WCAT= W_SCAT + SCAT_TOT;          // 1408*128 concatenated weights
constexpr size_t WC0=0, WC1=(size_t)384*128, WC2=WC1+(size_t)640*128;

__device__ __forceinline__ float wredf(float v){
  #pragma unroll
  for(int o=32;o;o>>=1) v += __shfl_xor(v,o,64);
  return v;
}
__device__ __forceinline__ int wredi(int v){
  #pragma unroll
  for(int o=32;o;o>>=1) v += __shfl_xor(v,o,64);
  return v;
}

// ---------------- weight prep: W*_s sums + concatenated weight stacks ----------------
__global__ void k_wprep(const float* Wd,const float* Wu,const float* Wh,
                        const float* Wb1,const float* Wb2, float* ws){
  int t = blockIdx.x*256 + threadIdx.x;
  if (t >= 16384) return;
  float sd = Wd[t]  + Wd[16384+t]  + Wd[32768+t];
  float su = Wu[t]  + Wu[16384+t]  + Wu[32768+t];
  float s1 = Wb1[t] + Wb1[16384+t] + Wb1[32768+t];
  float s2 = Wb2[t] + Wb2[16384+t] + Wb2[32768+t];
  float wh = Wh[t];
  float* W0 = ws + W_WCAT + WC0;
  float* W1 = ws + W_WCAT + WC1;
  float* W2 = ws + W_WCAT + WC2;
  W0[t]=sd; W0[16384+t]=s1; W0[32768+t]=wh;                       // [Wd;Wb1;Wh]
  W1[t]=sd; W1[16384+t]=su; W1[32768+t]=s1; W1[49152+t]=s2; W1[65536+t]=wh; // [Wd;Wu;Wb1;Wb2;Wh]
  W2[t]=su; W2[16384+t]=s2; W2[32768+t]=wh;                       // [Wu;Wb2;Wh]
}

// ---------------- CSR extraction ----------------
__device__ __forceinline__ void mat_meta(int wid, const float* L0,const float* L1d,const float* L1u,
    const float* L2,const float* B1,const float* B2,
    const float*& M,int& ncol,int& lrow,int& co,int& po,int& cb,int& cap){
  if (wid < 1024){ M=L0;  ncol=1024; lrow=wid;        co=C_L0;  po=P_L0;  cb=CB_L0;  cap=CAP_L0; }
  else if (wid < 4096){ M=L1d; ncol=3072; lrow=wid-1024;  co=C_L1D; po=P_L1D; cb=CB_L1D; cap=CAP_L1; }
  else if (wid < 7168){ M=L1u; ncol=3072; lrow=wid-4096;  co=C_L1U; po=P_L1U; cb=CB_L1U; cap=CAP_L1; }
  else if (wid < 9216){ M=L2;  ncol=2048; lrow=wid-7168;  co=C_L2;  po=P_L2;  cb=CB_L2;  cap=CAP_L2; }
  else if (wid < 10240){ M=B1; ncol=3072; lrow=wid-9216;  co=C_B1;  po=P_B1;  cb=CB_B1;  cap=CAP_B1; }
  else { M=B2; ncol=2048; lrow=wid-10240; co=C_B2;  po=P_B2;  cb=CB_B2;  cap=CAP_B2; }
}

__global__ void k_count(const float* L0,const float* L1d,const float* L1u,const float* L2,
                        const float* B1,const float* B2,int* cnt){
  int wid = blockIdx.x*4 + (threadIdx.x>>6);
  int lane = threadIdx.x & 63;
  if (wid >= 13312) return;
  const float* M; int ncol,lrow,co,po,cb,cap;
  mat_meta(wid,L0,L1d,L1u,L2,B1,B2,M,ncol,lrow,co,po,cb,cap);
  const float* row = M + (size_t)lrow*ncol;
  int c = 0;
  for (int j=lane; j<ncol; j+=64) c += (row[j]!=0.0f);
  c = wredi(c);
  if (lane==0) cnt[co+lrow] = c;
}

__global__ void k_prefix(const int* cnt, int* ptr){
  __shared__ int lds[257];
  const int rows[6]={1024,3072,3072,2048,1024,3072};
  const int cofs[6]={C_L0,C_L1D,C_L1U,C_L2,C_B1,C_B2};
  const int pofs[6]={P_L0,P_L1D,P_L1U,P_L2,P_B1,P_B2};
  int b=blockIdx.x, t=threadIdx.x;
  int R=rows[b]; const int* c=cnt+cofs[b]; int* p=ptr+pofs[b];
  int chunk=(R+255)/256;
  int lo=t*chunk, hi=min(R,lo+chunk);
  int s=0;
  for(int i=lo;i<hi;i++) s+=c[i];
  lds[t]=s; __syncthreads();
  if(t==0){ int run=0; for(int i=0;i<256;i++){int x=lds[i];lds[i]=run;run+=x;} lds[256]=run; }
  __syncthreads();
  int run=lds[t];
  for(int i=lo;i<hi;i++){ p[i]=run; run+=c[i]; }
  if(t==0) p[R]=lds[256];
}

__global__ void k_fill(const float* L0,const float* L1d,const float* L1u,const float* L2,
                       const float* B1,const float* B2,const int* ptr,int* cidx,float* val){
  int wid = blockIdx.x*4 + (threadIdx.x>>6);
  int lane = threadIdx.x & 63;
  if (wid >= 13312) return;
  const float* M; int ncol,lrow,co,po,cb,cap;
  mat_meta(wid,L0,L1d,L1u,L2,B1,B2,M,ncol,lrow,co,po,cb,cap);
  const float* row = M + (size_t)lrow*ncol;
  int base = ptr[po+lrow];
  int run = 0;
  for (int j0=0; j0<ncol; j0+=64){
    int j = j0 + lane;
    float v = (j<ncol)? row[j] : 0.0f;
    unsigned long long m = __ballot(v!=0.0f);
    if (v!=0.0f){
      int pos = base + run + __popcll(m & ((1ull<<lane)-1ull));
      if (pos < cap){ cidx[cb+pos]=j; val[cb+pos]=v; }
    }
    run += __popcll(m);
  }
}

// ---------------- init: zero V/ACC/SCAT, set v0 ----------------
__global__ void k_init(float* ws){
  size_t tid = (size_t)blockIdx.x*256 + threadIdx.x;
  size_t stride = (size_t)gridDim.x*256;
  for (size_t i=tid; i<6144; i+=stride){
    float invs;
    if (i<1024) invs = 0.03125f;             // 1/sqrt(1024)
    else if (i<4096) invs = 0.0180421959f;   // 1/sqrt(3072)
    else invs = 0.0220970869f;               // 1/sqrt(2048)
    unsigned u = (unsigned)i*2654435761u; u^=u>>16; u*=2246822519u; u^=u>>13;
    ws[W_V + i]          = (u&1)? invs : -invs;  // v0
    ws[W_V + 6144 + i]   = 0.f;                  // w slot
    ws[W_V + 12288 + i]  = 0.f;                  // v_{-1} = 0
  }
  for (size_t i=tid; i<(size_t)M_LZ*12; i+=stride) ws[W_ACC+i]=0.f;
  for (size_t i=tid; i<SCAT_TOT; i+=stride) ws[W_SCAT+i]=0.f;
}

// ---------------- Lanczos: matvec + dots ----------------
// 24 blocks: [0,4) cplx0 (N=1024), [4,16) cplx1 (N=3072, L1d+L1u), [16,24) cplx2 (N=2048)
__global__ __launch_bounds__(256) void k_lz_mv(float* ws, int j){
  int b=blockIdx.x, t=threadIdx.x;
  int c, lb, nbase, N;
  if (b<4){ c=0; lb=b; nbase=0; N=1024; }
  else if (b<16){ c=1; lb=b-4; nbase=1024; N=3072; }
  else { c=2; lb=b-16; nbase=4096; N=2048; }
  int p = lb*256 + t;
  int s_cur=j%3, s_prev=(j+2)%3, s_w=(j+1)%3;
  const float* vcur = ws + W_V + (size_t)s_cur*6144 + nbase;
  const float* vprev= ws + W_V + (size_t)s_prev*6144 + nbase;
  float* w          = ws + W_V + (size_t)s_w*6144 + nbase;
  const int* wsi = (const int*)ws;
  const int* ptr = wsi + W_PTR;
  const int* cidx= wsi + W_CIDX;
  const float* val = ws + W_VAL;
  float wp = 0.f;
  if (c==0){
    const int* rp = ptr + P_L0;
    for (int k=rp[p]; k<rp[p+1]; k++) wp += val[CB_L0+k]*vcur[cidx[CB_L0+k]];
  } else if (c==1){
    const int* rp = ptr + P_L1D;
    for (int k=rp[p]; k<rp[p+1]; k++) wp += val[CB_L1D+k]*vcur[cidx[CB_L1D+k]];
    const int* rq = ptr + P_L1U;
    for (int k=rq[p]; k<rq[p+1]; k++) wp += val[CB_L1U+k]*vcur[cidx[CB_L1U+k]];
  } else {
    const int* rp = ptr + P_L2;
    for (int k=rp[p]; k<rp[p+1]; k++) wp += val[CB_L2+k]*vcur[cidx[CB_L2+k]];
  }
  w[p] = wp;
  float a = vcur[p]*wp, g = vprev[p]*wp, n = wp*wp;
  a = wredf(a); g = wredf(g); n = wredf(n);
  __shared__ float red[3][4];
  int wv=t>>6, ln=t&63;
  if (ln==0){ red[0][wv]=a; red[1][wv]=g; red[2][wv]=n; }
  __syncthreads();
  if (t==0){
    float A=red[0][0]+red[0][1]+red[0][2]+red[0][3];
    float G=red[1][0]+red[1][1]+red[1][2]+red[1][3];
    float Nn=red[2][0]+red[2][1]+red[2][2]+red[2][3];
    atomicAdd(ws + W_ACC + (size_t)j*12 + c*4 + 0, A);
    atomicAdd(ws + W_ACC + (size_t)j*12 + c*4 + 1, G);
    atomicAdd(ws + W_ACC + (size_t)j*12 + c*4 + 2, Nn);
  }
}

// ---------------- Lanczos: update v_{j+1} = (w - a v - g v_prev)/beta ----------------
__global__ __launch_bounds__(256) void k_lz_up(float* ws, int j){
  int b=blockIdx.x, t=threadIdx.x;
  int c, lb, nbase;
  if (b<4){ c=0; lb=b; nbase=0; }
  else if (b<16){ c=1; lb=b-4; nbase=1024; }
  else { c=2; lb=b-16; nbase=4096; }
  int p = lb*256 + t;
  int s_cur=j%3, s_prev=(j+2)%3, s_w=(j+1)%3;
  float a = ws[W_ACC + (size_t)j*12 + c*4 + 0];
  float g = ws[W_ACC + (size_t)j*12 + c*4 + 1];
  float n = ws[W_ACC + (size_t)j*12 + c*4 + 2];
  float beta = sqrtf(fmaxf(n - a*a - g*g, 1e-20f));
  const float* vcur = ws + W_V + (size_t)s_cur*6144 + nbase;
  const float* vprev= ws + W_V + (size_t)s_prev*6144 + nbase;
  float* w          = ws + W_V + (size_t)s_w*6144 + nbase;
  w[p] = (w[p] - a*vcur[p] - g*vprev[p]) / beta;
  if (lb==0 && t==0){ ws[W_TA + (size_t)c*M_LZ + j]=a; ws[W_TB + (size_t)c*M_LZ + j]=beta; }
}

// ---------------- largest Ritz value via wave-parallel Sturm bisection ----------------
__global__ void k_eig(float* ws){
  int c = threadIdx.x>>6, lane = threadIdx.x&63;
  if (c>=3) return;
  const float* TA = ws + W_TA + (size_t)c*M_LZ;
  const float* TB = ws + W_TB + (size_t)c*M_LZ;
  double lo=1e300, hi=-1e300;
  for (int i=lane;i<M_LZ;i+=64){
    double r=(i? fabs((double)TB[i-1]):0.0) + (i<M_LZ-1? fabs((double)TB[i]):0.0);
    lo = fmin(lo,(double)TA[i]-r); hi = fmax(hi,(double)TA[i]+r);
  }
  #pragma unroll
  for(int o=32;o;o>>=1){ lo=fmin(lo,__shfl_xor(lo,o,64)); hi=fmax(hi,__shfl_xor(hi,o,64)); }
  lo -= 1.0; hi += 1.0;
  for (int round=0; round<4; round++){
    double x = lo + (hi-lo)*(double)(lane+1)/65.0;
    double d = 1.0; int cnt=0;
    for (int i=0;i<M_LZ;i++){
      double bi = i? (double)TB[i-1] : 0.0;
      d = ((double)TA[i]-x) - bi*bi/d;
      if (d==0.0) d = -1e-300;
      if (d<0.0) cnt++;
    }
    double nlo = (cnt< M_LZ)? x : -1e300;
    double nhi = (cnt==M_LZ)? x :  1e300;
    #pragma unroll
    for(int o=32;o;o>>=1){ nlo=fmax(nlo,__shfl_xor(nlo,o,64)); nhi=fmin(nhi,__shfl_xor(nhi,o,64)); }
    if (nlo>-1e299) lo=nlo;
    if (nhi< 1e299) hi=nhi;
  }
  double lam = 0.5*(lo+hi);
  if (lane==0) ws[W_EPS+c] = (lam>0.0)? (float)(1.0/lam) : 0.1f;
}

// ---------------- attention U,V vectors ----------------
__global__ void k_attn_uv(const float* z1, const float* wd, const float* wu, float* ws){
  int wid = blockIdx.x*4 + (threadIdx.x>>6);
  int lane = threadIdx.x & 63;
  if (wid>=3072) return;
  float2 x = ((const float2*)(z1 + (size_t)wid*128))[lane];
  float2 a0 = ((const float2*)wd)[lane];      // w[0:128]
  float2 a1 = ((const float2*)wd)[64+lane];   // w[128:256]
  float2 b0 = ((const float2*)wu)[lane];
  float2 b1 = ((const float2*)wu)[64+lane];
  float ud = x.x*a0.x + x.y*a0.y;
  float vd = x.x*a1.x + x.y*a1.y;
  float uu = x.x*b0.x + x.y*b0.y;
  float vu = x.x*b1.x + x.y*b1.y;
  ud=wredf(ud); vd=wredf(vd); uu=wredf(uu); vu=wredf(vu);
  if (lane==0){
    ws[W_UV+wid]=ud; ws[W_UV+3072+wid]=vd;
    ws[W_UV+6144+wid]=uu; ws[W_UV+9216+wid]=vu;
  }
}

// ---------------- harmonic step: y <- y - eps*(L y); step 15 writes staging ----------------
__global__ void k_harm(float* ws, const float* z0,const float* z1,const float* z2,int step){
  int b=blockIdx.x, t=threadIdx.x;
  int c, lb, nb;
  if(b<16){c=0;lb=b;nb=16;} else if(b<64){c=1;lb=b-16;nb=48;} else {c=2;lb=b-64;nb=32;}
  int lane=t&63, wv=t>>6;
  int wid=lb*4+wv, nw=nb*4;
  int N = (c==0)?1024:(c==1)?3072:2048;
  const float* z = (c==0)?z0:(c==1)?z1:z2;
  float eps = ws[W_EPS+c];
  size_t cb = (c==0)? 0 : (c==1)? (size_t)1024*128 : (size_t)4096*128;
  const float* in = (step==0)? z : ws + W_H + (size_t)((step-1)&1)*HBUF + cb;
  float* out; size_t ostride;
  if (step<15){ out = ws + W_H + (size_t)(step&1)*HBUF + cb; ostride=128; }
  else {
    if(c==0){ out=ws+W_SCAT+S0_OFF+256; ostride=384; }
    else if(c==1){ out=ws+W_SCAT+S1_OFF+512; ostride=640; }
    else { out=ws+W_SCAT+S2_OFF+256; ostride=384; }
  }
  const int* wsi=(const int*)ws;
  const int* ptr=wsi+W_PTR; const int* cidx=wsi+W_CIDX; const float* val=ws+W_VAL;
  for (int p=wid; p<N; p+=nw){
    float2 acc = ((const float2*)(in + (size_t)p*128))[lane];
    float2 s = {0.f,0.f};
    if (c==0){
      const int* rp=ptr+P_L0;
      for(int k=rp[p];k<rp[p+1];k++){
        float v=val[CB_L0+k]; int q=cidx[CB_L0+k];
        float2 xq=((const float2*)(in+(size_t)q*128))[lane];
        s.x+=v*xq.x; s.y+=v*xq.y;
      }
    } else if (c==1){
      const int* rp=ptr+P_L1D;
      for(int k=rp[p];k<rp[p+1];k++){
        float v=val[CB_L1D+k]; int q=cidx[CB_L1D+k];
        float2 xq=((const float2*)(in+(size_t)q*128))[lane];
        s.x+=v*xq.x; s.y+=v*xq.y;
      }
      const int* rq=ptr+P_L1U;
      for(int k=rq[p];k<rq[p+1];k++){
        float v=val[CB_L1U+k]; int q=cidx[CB_L1U+k];
        float2 xq=((const float2*)(in+(size_t)q*128))[lane];
        s.x+=v*xq.x; s.y+=v*xq.y;
      }
    } else {
      const int* rp=ptr+P_L2;
      for(int k=rp[p];k<rp[p+1];k++){
        float v=val[CB_L2+k]; int q=cidx[CB_L2+k];
        float2 xq=((const float2*)(in+(size_t)q*128))[lane];
        s.x+=v*xq.x; s.y+=v*xq.y;
      }
    }
    acc.x -= eps*s.x; acc.y -= eps*s.y;
    ((float2*)(out + (size_t)p*ostride))[lane] = acc;
  }
}

// ---------------- forward SpMMs into staging (incl. attention-valued) ----------------
__global__ void k_spmm_fwd(float* ws, const float* z0,const float* z1,const float* z2,
                           const float* bd, const float* bu){
  int wid = blockIdx.x*4 + (threadIdx.x>>6);
  int lane = threadIdx.x & 63;
  if (wid>=13312) return;
  int task, p;
  if(wid<1024){task=0;p=wid;}
  else if(wid<2048){task=1;p=wid-1024;}
  else if(wid<5120){task=2;p=wid-2048;}
  else if(wid<8192){task=3;p=wid-5120;}
  else if(wid<11264){task=4;p=wid-8192;}
  else {task=5;p=wid-11264;}
  const int* wsi=(const int*)ws;
  const int* ptr=wsi+W_PTR; const int* cidx=wsi+W_CIDX; const float* val=ws+W_VAL;
  const float* in; const int* rp; int cb; float* out; int ostride;
  int mode=0; float Vp=0.f, bb=0.f; const float* U=nullptr;
  switch(task){
    case 0: rp=ptr+P_L0;  cb=CB_L0;  in=z0; out=ws+W_SCAT+S0_OFF+0;   ostride=384; break;
    case 1: rp=ptr+P_B1;  cb=CB_B1;  in=z1; out=ws+W_SCAT+S0_OFF+128; ostride=384; break;
    case 2: rp=ptr+P_L1D; cb=CB_L1D; in=z1; out=ws+W_SCAT+S1_OFF+0;   ostride=640;
            mode=1; U=ws+W_UV; Vp=ws[W_UV+3072+p]; bb=bd[0]; break;
    case 3: rp=ptr+P_L1U; cb=CB_L1U; in=z1; out=ws+W_SCAT+S1_OFF+128; ostride=640;
            mode=1; U=ws+W_UV+6144; Vp=ws[W_UV+9216+p]; bb=bu[0]; break;
    case 4: rp=ptr+P_B2;  cb=CB_B2;  in=z2; out=ws+W_SCAT+S1_OFF+384; ostride=640; break;
    default:rp=ptr+P_L2;  cb=CB_L2;  in=z2; out=ws+W_SCAT+S2_OFF+0;   ostride=384; break;
  }
  float2 s={0.f,0.f};
  for (int k=rp[p]; k<rp[p+1]; k++){
    int q = cidx[cb+k];
    float v;
    if (mode) v = 1.0f/(1.0f+__expf(-(U[q]+Vp+bb)));   // A[p,q] = sigma(U_q + V_p + b)
    else v = val[cb+k];
    float2 xq = ((const float2*)(in+(size_t)q*128))[lane];
    s.x += v*xq.x; s.y += v*xq.y;
  }
  ((float2*)(out + (size_t)p*ostride))[lane] = s;
}

// ---------------- transpose SpMMs (B1^T z0, B2^T z1) via atomic scatter ----------------
__global__ void k_spmm_scatter(float* ws, const float* z0,const float* z1){
  int wid = blockIdx.x*4 + (threadIdx.x>>6);
  int lane = threadIdx.x & 63;
  const int* wsi=(const int*)ws;
  const int* ptr=wsi+W_PTR; const int* cidx=wsi+W_CIDX; const float* val=ws+W_VAL;
  if (wid < 1024){            // B1 row q -> Scat1 cols [256,384)
    int q=wid;
    const int* rp=ptr+P_B1;
    float2 x=((const float2*)(z0+(size_t)q*128))[lane];
    float* out=ws+W_SCAT+S1_OFF+256;
    for(int k=rp[q];k<rp[q+1];k++){
      int p=cidx[CB_B1+k]; float v=val[CB_B1+k];
      atomicAdd(out+(size_t)p*640+2*lane,   v*x.x);
      atomicAdd(out+(size_t)p*640+2*lane+1, v*x.y);
    }
  } else if (wid < 4096){     // B2 row q -> Scat2 cols [128,256)
    int q=wid-1024;
    const int* rp=ptr+P_B2;
    float2 x=((const float2*)(z1+(size_t)q*128))[lane];
    float* out=ws+W_SCAT+S2_OFF+128;
    for(int k=rp[q];k<rp[q+1];k++){
      int p=cidx[CB_B2+k]; float v=val[CB_B2+k];
      atomicAdd(out+(size_t)p*384+2*lane,   v*x.x);
      atomicAdd(out+(size_t)p*384+2*lane+1, v*x.y);
    }
  }
}

// ---------------- projection GEMM: out = relu(S @ Wcat), N=128 ----------------
__global__ __launch_bounds__(256) void k_gemm(const float* S, const float* W, float* out, int M, int K){
  __shared__ float Sl[32][33];
  __shared__ float Wl[32][128];
  int t=threadIdx.x;
  int r0=blockIdx.x*32;
  int ty=t>>5, tx=t&31;
  float acc[4][4]={};
  for (int k0=0; k0<K; k0+=32){
    {
      int r=t>>3, kq=(t&7)*4;
      const float* src=S+(size_t)(r0+r)*K + k0+kq;
      Sl[r][kq]=src[0]; Sl[r][kq+1]=src[1]; Sl[r][kq+2]=src[2]; Sl[r][kq+3]=src[3];
    }
    {
      int kk=t>>4, cq=(t&15)*8;
      #pragma unroll
      for(int h=0;h<2;h++){
        const float* src=W+(size_t)(k0+kk+16*h)*128+cq;
        #pragma unroll
        for(int i=0;i<8;i++) Wl[kk+16*h][cq+i]=src[i];
      }
    }
    __syncthreads();
    #pragma unroll
    for(int k=0;k<32;k++){
      float sv[4], wv[4];
      #pragma unroll
      for(int i=0;i<4;i++) sv[i]=Sl[ty*4+i][k];
      #pragma unroll
      for(int i=0;i<4;i++) wv[i]=Wl[k][tx+32*i];
      #pragma unroll
      for(int a=0;a<4;a++)
        #pragma unroll
        for(int b2=0;b2<4;b2++) acc[a][b2]+=sv[a]*wv[b2];
    }
    __syncthreads();
  }
  #pragma unroll
  for(int a=0;a<4;a++)
    #pragma unroll
    for(int b2=0;b2<4;b2++){
      int r=r0+ty*4+a, col=tx+32*b2;
      out[(size_t)r*128+col]=fmaxf(acc[a][b2],0.f);
    }
}

// ---------------- host ----------------
extern "C" void kernel_launch(void* const* d_in, const int* in_sizes, int n_in,
                              void* d_out, int out_size, void* d_ws, size_t ws_size,
                              hipStream_t stream){
  const float* z0 =(const float*)d_in[0];
  const float* z1 =(const float*)d_in[1];
  const float* z2 =(const float*)d_in[2];
  const float* L0 =(const float*)d_in[3];
  const float* L1d=(const float*)d_in[4];
  const float* L1u=(const float*)d_in[5];
  const float* L2 =(const float*)d_in[6];
  const float* B1 =(const float*)d_in[7];
  const float* B2 =(const float*)d_in[8];
  const float* Wd =(const float*)d_in[9];
  const float* Wu =(const float*)d_in[10];
  const float* Wh =(const float*)d_in[11];
  const float* Wb1=(const float*)d_in[12];
  const float* Wb2=(const float*)d_in[13];
  const float* adw=(const float*)d_in[14];
  const float* adb=(const float*)d_in[15];
  const float* auw=(const float*)d_in[16];
  const float* aub=(const float*)d_in[17];
  float* ws=(float*)d_ws;
  int* wsi=(int*)d_ws;
  float* out=(float*)d_out;

  hipLaunchKernelGGL(k_wprep, dim3(64), dim3(256), 0, stream, Wd,Wu,Wh,Wb1,Wb2,ws);
  hipLaunchKernelGGL(k_count, dim3(3328), dim3(256), 0, stream, L0,L1d,L1u,L2,B1,B2, wsi+W_CNT);
  hipLaunchKernelGGL(k_prefix, dim3(6), dim3(256), 0, stream, wsi+W_CNT, wsi+W_PTR);
  hipLaunchKernelGGL(k_fill, dim3(3328), dim3(256), 0, stream, L0,L1d,L1u,L2,B1,B2, wsi+W_PTR, wsi+W_CIDX, ws+W_VAL);
  hipLaunchKernelGGL(k_init, dim3(1024), dim3(256), 0, stream, ws);
  for (int j=0;j<M_LZ;j++){
    hipLaunchKernelGGL(k_lz_mv, dim3(24), dim3(256), 0, stream, ws, j);
    hipLaunchKernelGGL(k_lz_up, dim3(24), dim3(256), 0, stream, ws, j);
  }
  hipLaunchKernelGGL(k_eig, dim3(1), dim3(256), 0, stream, ws);
  hipLaunchKernelGGL(k_attn_uv, dim3(768), dim3(256), 0, stream, z1, adw, auw, ws);
  for (int s=0;s<16;s++)
    hipLaunchKernelGGL(k_harm, dim3(96), dim3(256), 0, stream, ws, z0,z1,z2, s);
  hipLaunchKernelGGL(k_spmm_fwd, dim3(3328), dim3(256), 0, stream, ws, z0,z1,z2, adb, aub);
  hipLaunchKernelGGL(k_spmm_scatter, dim3(1024), dim3(256), 0, stream, ws, z0, z1);
  hipLaunchKernelGGL(k_gemm, dim3(32), dim3(256), 0, stream, ws+W_SCAT+S0_OFF, ws+W_WCAT+WC0, out,          1024, 384);
  hipLaunchKernelGGL(k_gemm, dim3(96), dim3(256), 0, stream, ws+W_SCAT+S1_OFF, ws+W_WCAT+WC1, out+131072,   3072, 640);
  hipLaunchKernelGGL(k_gemm, dim3(64), dim3(256), 0, stream, ws+W_SCAT+S2_OFF, ws+W_WCAT+WC2, out+524288,   2048, 384);
}

// Round 2
// 3858.298 us; speedup vs baseline: 2.0960x; 2.0960x over previous
//
#include <hip/hip_runtime.h>

// ---------------- problem constants ----------------
constexpr int M_LZ = 96;           // Lanczos steps

// CSR capacity per matrix (expected nnz * ~1.25)
constexpr int CAP_L0 = 26240, CAP_L1 = 118016, CAP_L2 = 52480, CAP_B1 = 39360, CAP_B2 = 78720;
constexpr int CB_L0 = 0;
constexpr int CB_L1D = CB_L0 + CAP_L0;
constexpr int CB_L1U = CB_L1D + CAP_L1;
constexpr int CB_L2  = CB_L1U + CAP_L1;
constexpr int CB_B1  = CB_L2 + CAP_L2;
constexpr int CB_B2  = CB_B1 + CAP_B1;
constexpr int CAP_TOT= CB_B2 + CAP_B2;   // 432832

// rowptr offsets (ints) within W_PTR region
constexpr int P_L0=0, P_L1D=1025, P_L1U=4098, P_L2=7171, P_B1=9220, P_B2=10245;
// row-count offsets within W_CNT region
constexpr int C_L0=0, C_L1D=1024, C_L1U=4096, C_L2=7168, C_B1=9216, C_B2=10240;

// workspace layout (units: 4-byte words)
constexpr size_t W_CNT = 0;                         // 13312 ints
constexpr size_t W_PTR = 13312;                     // 13320 ints
constexpr size_t W_CIDX= W_PTR + 13320;             // CAP_TOT ints
constexpr size_t W_VAL = W_CIDX + CAP_TOT;          // CAP_TOT floats
constexpr size_t W_V   = W_VAL + CAP_TOT;           // 3 slots * 6144 (lanczos vectors)
constexpr size_t W_ACC = W_V + 3*6144;              // M_LZ*96 (bucketed dot accumulators)
constexpr size_t W_TA  = W_ACC + (size_t)M_LZ*96;   // 3*M_LZ (tridiag alpha)
constexpr size_t W_TB  = W_TA + 3*M_LZ;             // 3*M_LZ (tridiag beta)
constexpr size_t W_EPS = W_TB + 3*M_LZ;             // 4
constexpr size_t W_UV  = W_EPS + 4;                 // 4*3072 (U_d,V_d,U_u,V_u)
constexpr size_t HBUF  = (size_t)6144*128;
constexpr size_t W_H   = W_UV + 4*3072;             // 2 ping-pong harmonic buffers
constexpr size_t W_SCAT= W_H + 2*HBUF;
constexpr size_t S0_OFF= 0;                          // 1024 x 384
constexpr size_t S1_OFF= (size_t)1024*384;           // 3072 x 640
constexpr size_t S2_OFF= S1_OFF + (size_t)3072*640;  // 2048 x 384
constexpr size_t SCAT_TOT = S2_OFF + (size_t)2048*384;
constexpr size_t W_WCAT= W_SCAT + SCAT_TOT;          // 1408*128 concatenated weights
constexpr size_t WC0=0, WC1=(size_t)384*128, WC2=WC1+(size_t)640*128;

__device__ __forceinline__ float wredf(float v){
  #pragma unroll
  for(int o=32;o;o>>=1) v += __shfl_xor(v,o,64);
  return v;
}
__device__ __forceinline__ int wredi(int v){
  #pragma unroll
  for(int o=32;o;o>>=1) v += __shfl_xor(v,o,64);
  return v;
}

// ---------------- weight prep: W*_s sums + concatenated weight stacks ----------------
__global__ void k_wprep(const float* Wd,const float* Wu,const float* Wh,
                        const float* Wb1,const float* Wb2, float* ws){
  int t = blockIdx.x*256 + threadIdx.x;
  if (t >= 16384) return;
  float sd = Wd[t]  + Wd[16384+t]  + Wd[32768+t];
  float su = Wu[t]  + Wu[16384+t]  + Wu[32768+t];
  float s1 = Wb1[t] + Wb1[16384+t] + Wb1[32768+t];
  float s2 = Wb2[t] + Wb2[16384+t] + Wb2[32768+t];
  float wh = Wh[t];
  float* W0 = ws + W_WCAT + WC0;
  float* W1 = ws + W_WCAT + WC1;
  float* W2 = ws + W_WCAT + WC2;
  W0[t]=sd; W0[16384+t]=s1; W0[32768+t]=wh;                       // [Wd;Wb1;Wh]
  W1[t]=sd; W1[16384+t]=su; W1[32768+t]=s1; W1[49152+t]=s2; W1[65536+t]=wh; // [Wd;Wu;Wb1;Wb2;Wh]
  W2[t]=su; W2[16384+t]=s2; W2[32768+t]=wh;                       // [Wu;Wb2;Wh]
}

// ---------------- CSR extraction ----------------
__device__ __forceinline__ void mat_meta(int wid, const float* L0,const float* L1d,const float* L1u,
    const float* L2,const float* B1,const float* B2,
    const float*& M,int& ncol,int& lrow,int& co,int& po,int& cb,int& cap){
  if (wid < 1024){ M=L0;  ncol=1024; lrow=wid;        co=C_L0;  po=P_L0;  cb=CB_L0;  cap=CAP_L0; }
  else if (wid < 4096){ M=L1d; ncol=3072; lrow=wid-1024;  co=C_L1D; po=P_L1D; cb=CB_L1D; cap=CAP_L1; }
  else if (wid < 7168){ M=L1u; ncol=3072; lrow=wid-4096;  co=C_L1U; po=P_L1U; cb=CB_L1U; cap=CAP_L1; }
  else if (wid < 9216){ M=L2;  ncol=2048; lrow=wid-7168;  co=C_L2;  po=P_L2;  cb=CB_L2;  cap=CAP_L2; }
  else if (wid < 10240){ M=B1; ncol=3072; lrow=wid-9216;  co=C_B1;  po=P_B1;  cb=CB_B1;  cap=CAP_B1; }
  else { M=B2; ncol=2048; lrow=wid-10240; co=C_B2;  po=P_B2;  cb=CB_B2;  cap=CAP_B2; }
}

__global__ void k_count(const float* L0,const float* L1d,const float* L1u,const float* L2,
                        const float* B1,const float* B2,int* cnt){
  int wid = blockIdx.x*4 + (threadIdx.x>>6);
  int lane = threadIdx.x & 63;
  if (wid >= 13312) return;
  const float* M; int ncol,lrow,co,po,cb,cap;
  mat_meta(wid,L0,L1d,L1u,L2,B1,B2,M,ncol,lrow,co,po,cb,cap);
  const float* row = M + (size_t)lrow*ncol;
  int c = 0;
  for (int j=lane; j<ncol; j+=64) c += (row[j]!=0.0f);
  c = wredi(c);
  if (lane==0) cnt[co+lrow] = c;
}

__global__ void k_prefix(const int* cnt, int* ptr){
  __shared__ int lds[257];
  const int rows[6]={1024,3072,3072,2048,1024,3072};
  const int cofs[6]={C_L0,C_L1D,C_L1U,C_L2,C_B1,C_B2};
  const int pofs[6]={P_L0,P_L1D,P_L1U,P_L2,P_B1,P_B2};
  int b=blockIdx.x, t=threadIdx.x;
  int R=rows[b]; const int* c=cnt+cofs[b]; int* p=ptr+pofs[b];
  int chunk=(R+255)/256;
  int lo=t*chunk, hi=min(R,lo+chunk);
  int s=0;
  for(int i=lo;i<hi;i++) s+=c[i];
  lds[t]=s; __syncthreads();
  if(t==0){ int run=0; for(int i=0;i<256;i++){int x=lds[i];lds[i]=run;run+=x;} lds[256]=run; }
  __syncthreads();
  int run=lds[t];
  for(int i=lo;i<hi;i++){ p[i]=run; run+=c[i]; }
  if(t==0) p[R]=lds[256];
}

__global__ void k_fill(const float* L0,const float* L1d,const float* L1u,const float* L2,
                       const float* B1,const float* B2,const int* ptr,int* cidx,float* val){
  int wid = blockIdx.x*4 + (threadIdx.x>>6);
  int lane = threadIdx.x & 63;
  if (wid >= 13312) return;
  const float* M; int ncol,lrow,co,po,cb,cap;
  mat_meta(wid,L0,L1d,L1u,L2,B1,B2,M,ncol,lrow,co,po,cb,cap);
  const float* row = M + (size_t)lrow*ncol;
  int base = ptr[po+lrow];
  int run = 0;
  for (int j0=0; j0<ncol; j0+=64){
    int j = j0 + lane;
    float v = (j<ncol)? row[j] : 0.0f;
    unsigned long long m = __ballot(v!=0.0f);
    if (v!=0.0f){
      int pos = base + run + __popcll(m & ((1ull<<lane)-1ull));
      if (pos < cap){ cidx[cb+pos]=j; val[cb+pos]=v; }
    }
    run += __popcll(m);
  }
}

// ---------------- init: zero V/ACC/SCAT, set v0 ----------------
__global__ void k_init(float* ws){
  size_t tid = (size_t)blockIdx.x*256 + threadIdx.x;
  size_t stride = (size_t)gridDim.x*256;
  for (size_t i=tid; i<6144; i+=stride){
    float invs;
    if (i<1024) invs = 0.03125f;             // 1/sqrt(1024)
    else if (i<4096) invs = 0.0180421959f;   // 1/sqrt(3072)
    else invs = 0.0220970869f;               // 1/sqrt(2048)
    unsigned u = (unsigned)i*2654435761u; u^=u>>16; u*=2246822519u; u^=u>>13;
    ws[W_V + i]          = (u&1)? invs : -invs;  // v0
    ws[W_V + 6144 + i]   = 0.f;                  // w slot
    ws[W_V + 12288 + i]  = 0.f;                  // v_{-1} = 0
  }
  for (size_t i=tid; i<(size_t)M_LZ*96; i+=stride) ws[W_ACC+i]=0.f;
  for (size_t i=tid; i<SCAT_TOT; i+=stride) ws[W_SCAT+i]=0.f;
}

// ---------------- Lanczos: matvec + dots (one WAVE per row; lanes parallel over nnz) ----
// grid 1536x256 -> 6144 waves; block of 4 consecutive rows is always within one complex
__global__ __launch_bounds__(256) void k_lz_mv(float* ws, int j){
  int wid = blockIdx.x*4 + (threadIdx.x>>6);   // global row 0..6143
  int lane = threadIdx.x & 63;
  int c, p, nbase;
  if (wid<1024){ c=0; p=wid;      nbase=0; }
  else if (wid<4096){ c=1; p=wid-1024; nbase=1024; }
  else { c=2; p=wid-4096; nbase=4096; }
  int s_cur=j%3, s_prev=(j+2)%3, s_w=(j+1)%3;
  const float* vcur = ws + W_V + (size_t)s_cur*6144 + nbase;
  const float* vprev= ws + W_V + (size_t)s_prev*6144 + nbase;
  float* w          = ws + W_V + (size_t)s_w*6144 + nbase;
  const int* wsi = (const int*)ws;
  const int* ptr = wsi + W_PTR;
  const int* cidx= wsi + W_CIDX;
  const float* val = ws + W_VAL;
  float wp = 0.f;
  if (c==0){
    const int* rp = ptr + P_L0; int e=rp[p+1];
    for (int k=rp[p]+lane; k<e; k+=64) wp += val[CB_L0+k]*vcur[cidx[CB_L0+k]];
  } else if (c==1){
    const int* rp = ptr + P_L1D; int e=rp[p+1];
    for (int k=rp[p]+lane; k<e; k+=64) wp += val[CB_L1D+k]*vcur[cidx[CB_L1D+k]];
    const int* rq = ptr + P_L1U; int e2=rq[p+1];
    for (int k=rq[p]+lane; k<e2; k+=64) wp += val[CB_L1U+k]*vcur[cidx[CB_L1U+k]];
  } else {
    const int* rp = ptr + P_L2; int e=rp[p+1];
    for (int k=rp[p]+lane; k<e; k+=64) wp += val[CB_L2+k]*vcur[cidx[CB_L2+k]];
  }
  wp = wredf(wp);
  __shared__ float red[3][4];
  int wv = threadIdx.x>>6;
  if (lane==0){
    w[p] = wp;
    float vc = vcur[p], vp = vprev[p];
    red[0][wv] = vc*wp;
    red[1][wv] = vp*wp;
    red[2][wv] = wp*wp;
  }
  __syncthreads();
  if (threadIdx.x==0){
    float A = red[0][0]+red[0][1]+red[0][2]+red[0][3];
    float G = red[1][0]+red[1][1]+red[1][2]+red[1][3];
    float Nn= red[2][0]+red[2][1]+red[2][2]+red[2][3];
    int bucket = blockIdx.x & 7;
    float* acc = ws + W_ACC + (size_t)j*96 + (size_t)c*24;
    atomicAdd(acc + 0*8 + bucket, A);
    atomicAdd(acc + 1*8 + bucket, G);
    atomicAdd(acc + 2*8 + bucket, Nn);
  }
}

// ---------------- Lanczos: update v_{j+1} = (w - a v - g v_prev)/beta ----------------
__global__ __launch_bounds__(256) void k_lz_up(float* ws, int j){
  int b=blockIdx.x, t=threadIdx.x;
  int c, lb, nbase;
  if (b<4){ c=0; lb=b; nbase=0; }
  else if (b<16){ c=1; lb=b-4; nbase=1024; }
  else { c=2; lb=b-16; nbase=4096; }
  int p = lb*256 + t;
  int s_cur=j%3, s_prev=(j+2)%3, s_w=(j+1)%3;
  const float* A = ws + W_ACC + (size_t)j*96 + (size_t)c*24;
  float a=0.f, g=0.f, n=0.f;
  #pragma unroll
  for (int bkt=0;bkt<8;bkt++){ a+=A[bkt]; g+=A[8+bkt]; n+=A[16+bkt]; }
  float beta = sqrtf(fmaxf(n - a*a - g*g, 1e-20f));
  const float* vcur = ws + W_V + (size_t)s_cur*6144 + nbase;
  const float* vprev= ws + W_V + (size_t)s_prev*6144 + nbase;
  float* w          = ws + W_V + (size_t)s_w*6144 + nbase;
  w[p] = (w[p] - a*vcur[p] - g*vprev[p]) / beta;
  if (lb==0 && t==0){ ws[W_TA + (size_t)c*M_LZ + j]=a; ws[W_TB + (size_t)c*M_LZ + j]=beta; }
}

// ---------------- largest Ritz value via wave-parallel Sturm bisection ----------------
__global__ void k_eig(float* ws){
  int c = threadIdx.x>>6, lane = threadIdx.x&63;
  if (c>=3) return;
  const float* TA = ws + W_TA + (size_t)c*M_LZ;
  const float* TB = ws + W_TB + (size_t)c*M_LZ;
  double lo=1e300, hi=-1e300;
  for (int i=lane;i<M_LZ;i+=64){
    double r=(i? fabs((double)TB[i-1]):0.0) + (i<M_LZ-1? fabs((double)TB[i]):0.0);
    lo = fmin(lo,(double)TA[i]-r); hi = fmax(hi,(double)TA[i]+r);
  }
  #pragma unroll
  for(int o=32;o;o>>=1){ lo=fmin(lo,__shfl_xor(lo,o,64)); hi=fmax(hi,__shfl_xor(hi,o,64)); }
  lo -= 1.0; hi += 1.0;
  for (int round=0; round<4; round++){
    double x = lo + (hi-lo)*(double)(lane+1)/65.0;
    double d = 1.0; int cnt=0;
    for (int i=0;i<M_LZ;i++){
      double bi = i? (double)TB[i-1] : 0.0;
      d = ((double)TA[i]-x) - bi*bi/d;
      if (d==0.0) d = -1e-300;
      if (d<0.0) cnt++;
    }
    double nlo = (cnt< M_LZ)? x : -1e300;
    double nhi = (cnt==M_LZ)? x :  1e300;
    #pragma unroll
    for(int o=32;o;o>>=1){ nlo=fmax(nlo,__shfl_xor(nlo,o,64)); nhi=fmin(nhi,__shfl_xor(nhi,o,64)); }
    if (nlo>-1e299) lo=nlo;
    if (nhi< 1e299) hi=nhi;
  }
  double lam = 0.5*(lo+hi);
  if (lane==0) ws[W_EPS+c] = (lam>0.0)? (float)(1.0/lam) : 0.1f;
}

// ---------------- attention U,V vectors ----------------
__global__ void k_attn_uv(const float* z1, const float* wd, const float* wu, float* ws){
  int wid = blockIdx.x*4 + (threadIdx.x>>6);
  int lane = threadIdx.x & 63;
  if (wid>=3072) return;
  float2 x = ((const float2*)(z1 + (size_t)wid*128))[lane];
  float2 a0 = ((const float2*)wd)[lane];      // w[0:128]
  float2 a1 = ((const float2*)wd)[64+lane];   // w[128:256]
  float2 b0 = ((const float2*)wu)[lane];
  float2 b1 = ((const float2*)wu)[64+lane];
  float ud = x.x*a0.x + x.y*a0.y;
  float vd = x.x*a1.x + x.y*a1.y;
  float uu = x.x*b0.x + x.y*b0.y;
  float vu = x.x*b1.x + x.y*b1.y;
  ud=wredf(ud); vd=wredf(vd); uu=wredf(uu); vu=wredf(vu);
  if (lane==0){
    ws[W_UV+wid]=ud; ws[W_UV+3072+wid]=vd;
    ws[W_UV+6144+wid]=uu; ws[W_UV+9216+wid]=vu;
  }
}

// ---------------- harmonic step: y <- y - eps*(L y); one WAVE per row --------------
// grid 1536x256 -> 6144 waves; step 15 writes into staging layout
__global__ __launch_bounds__(256) void k_harm(float* ws, const float* z0,const float* z1,const float* z2,int step){
  int wid = blockIdx.x*4 + (threadIdx.x>>6);
  int lane = threadIdx.x & 63;
  int c, p;
  if (wid<1024){ c=0; p=wid; }
  else if (wid<4096){ c=1; p=wid-1024; }
  else { c=2; p=wid-4096; }
  const float* z = (c==0)?z0:(c==1)?z1:z2;
  float eps = ws[W_EPS+c];
  size_t cb = (c==0)? 0 : (c==1)? (size_t)1024*128 : (size_t)4096*128;
  const float* in = (step==0)? z : ws + W_H + (size_t)((step-1)&1)*HBUF + cb;
  float* out; size_t ostride;
  if (step<15){ out = ws + W_H + (size_t)(step&1)*HBUF + cb; ostride=128; }
  else {
    if(c==0){ out=ws+W_SCAT+S0_OFF+256; ostride=384; }
    else if(c==1){ out=ws+W_SCAT+S1_OFF+512; ostride=640; }
    else { out=ws+W_SCAT+S2_OFF+256; ostride=384; }
  }
  const int* wsi=(const int*)ws;
  const int* ptr=wsi+W_PTR; const int* cidx=wsi+W_CIDX; const float* val=ws+W_VAL;
  float2 acc = ((const float2*)(in + (size_t)p*128))[lane];
  float2 s = {0.f,0.f};
  if (c==0){
    const int* rp=ptr+P_L0; int e=rp[p+1];
    for(int k=rp[p];k<e;k++){
      float v=val[CB_L0+k]; int q=cidx[CB_L0+k];
      float2 xq=((const float2*)(in+(size_t)q*128))[lane];
      s.x+=v*xq.x; s.y+=v*xq.y;
    }
  } else if (c==1){
    const int* rp=ptr+P_L1D; int e=rp[p+1];
    for(int k=rp[p];k<e;k++){
      float v=val[CB_L1D+k]; int q=cidx[CB_L1D+k];
      float2 xq=((const float2*)(in+(size_t)q*128))[lane];
      s.x+=v*xq.x; s.y+=v*xq.y;
    }
    const int* rq=ptr+P_L1U; int e2=rq[p+1];
    for(int k=rq[p];k<e2;k++){
      float v=val[CB_L1U+k]; int q=cidx[CB_L1U+k];
      float2 xq=((const float2*)(in+(size_t)q*128))[lane];
      s.x+=v*xq.x; s.y+=v*xq.y;
    }
  } else {
    const int* rp=ptr+P_L2; int e=rp[p+1];
    for(int k=rp[p];k<e;k++){
      float v=val[CB_L2+k]; int q=cidx[CB_L2+k];
      float2 xq=((const float2*)(in+(size_t)q*128))[lane];
      s.x+=v*xq.x; s.y+=v*xq.y;
    }
  }
  acc.x -= eps*s.x; acc.y -= eps*s.y;
  ((float2*)(out + (size_t)p*ostride))[lane] = acc;
}

// ---------------- forward SpMMs into staging (incl. attention-valued) ----------------
__global__ void k_spmm_fwd(float* ws, const float* z0,const float* z1,const float* z2,
                           const float* bd, const float* bu){
  int wid = blockIdx.x*4 + (threadIdx.x>>6);
  int lane = threadIdx.x & 63;
  if (wid>=13312) return;
  int task, p;
  if(wid<1024){task=0;p=wid;}
  else if(wid<2048){task=1;p=wid-1024;}
  else if(wid<5120){task=2;p=wid-2048;}
  else if(wid<8192){task=3;p=wid-5120;}
  else if(wid<11264){task=4;p=wid-8192;}
  else {task=5;p=wid-11264;}
  const int* wsi=(const int*)ws;
  const int* ptr=wsi+W_PTR; const int* cidx=wsi+W_CIDX; const float* val=ws+W_VAL;
  const float* in; const int* rp; int cb; float* out; int ostride;
  int mode=0; float Vp=0.f, bb=0.f; const float* U=nullptr;
  switch(task){
    case 0: rp=ptr+P_L0;  cb=CB_L0;  in=z0; out=ws+W_SCAT+S0_OFF+0;   ostride=384; break;
    case 1: rp=ptr+P_B1;  cb=CB_B1;  in=z1; out=ws+W_SCAT+S0_OFF+128; ostride=384; break;
    case 2: rp=ptr+P_L1D; cb=CB_L1D; in=z1; out=ws+W_SCAT+S1_OFF+0;   ostride=640;
            mode=1; U=ws+W_UV; Vp=ws[W_UV+3072+p]; bb=bd[0]; break;
    case 3: rp=ptr+P_L1U; cb=CB_L1U; in=z1; out=ws+W_SCAT+S1_OFF+128; ostride=640;
            mode=1; U=ws+W_UV+6144; Vp=ws[W_UV+9216+p]; bb=bu[0]; break;
    case 4: rp=ptr+P_B2;  cb=CB_B2;  in=z2; out=ws+W_SCAT+S1_OFF+384; ostride=640; break;
    default:rp=ptr+P_L2;  cb=CB_L2;  in=z2; out=ws+W_SCAT+S2_OFF+0;   ostride=384; break;
  }
  float2 s={0.f,0.f};
  for (int k=rp[p]; k<rp[p+1]; k++){
    int q = cidx[cb+k];
    float v;
    if (mode) v = 1.0f/(1.0f+__expf(-(U[q]+Vp+bb)));   // A[p,q] = sigma(U_q + V_p + b)
    else v = val[cb+k];
    float2 xq = ((const float2*)(in+(size_t)q*128))[lane];
    s.x += v*xq.x; s.y += v*xq.y;
  }
  ((float2*)(out + (size_t)p*ostride))[lane] = s;
}

// ---------------- transpose SpMMs (B1^T z0, B2^T z1) via atomic scatter ----------------
__global__ void k_spmm_scatter(float* ws, const float* z0,const float* z1){
  int wid = blockIdx.x*4 + (threadIdx.x>>6);
  int lane = threadIdx.x & 63;
  const int* wsi=(const int*)ws;
  const int* ptr=wsi+W_PTR; const int* cidx=wsi+W_CIDX; const float* val=ws+W_VAL;
  if (wid < 1024){            // B1 row q -> Scat1 cols [256,384)
    int q=wid;
    const int* rp=ptr+P_B1;
    float2 x=((const float2*)(z0+(size_t)q*128))[lane];
    float* out=ws+W_SCAT+S1_OFF+256;
    for(int k=rp[q];k<rp[q+1];k++){
      int p=cidx[CB_B1+k]; float v=val[CB_B1+k];
      atomicAdd(out+(size_t)p*640+2*lane,   v*x.x);
      atomicAdd(out+(size_t)p*640+2*lane+1, v*x.y);
    }
  } else if (wid < 4096){     // B2 row q -> Scat2 cols [128,256)
    int q=wid-1024;
    const int* rp=ptr+P_B2;
    float2 x=((const float2*)(z1+(size_t)q*128))[lane];
    float* out=ws+W_SCAT+S2_OFF+128;
    for(int k=rp[q];k<rp[q+1];k++){
      int p=cidx[CB_B2+k]; float v=val[CB_B2+k];
      atomicAdd(out+(size_t)p*384+2*lane,   v*x.x);
      atomicAdd(out+(size_t)p*384+2*lane+1, v*x.y);
    }
  }
}

// ---------------- projection GEMM: out = relu(S @ Wcat), N=128 ----------------
__global__ __launch_bounds__(256) void k_gemm(const float* S, const float* W, float* out, int M, int K){
  __shared__ float Sl[32][33];
  __shared__ float Wl[32][128];
  int t=threadIdx.x;
  int r0=blockIdx.x*32;
  int ty=t>>5, tx=t&31;
  float acc[4][4]={};
  for (int k0=0; k0<K; k0+=32){
    {
      int r=t>>3, kq=(t&7)*4;
      const float* src=S+(size_t)(r0+r)*K + k0+kq;
      Sl[r][kq]=src[0]; Sl[r][kq+1]=src[1]; Sl[r][kq+2]=src[2]; Sl[r][kq+3]=src[3];
    }
    {
      int kk=t>>4, cq=(t&15)*8;
      #pragma unroll
      for(int h=0;h<2;h++){
        const float* src=W+(size_t)(k0+kk+16*h)*128+cq;
        #pragma unroll
        for(int i=0;i<8;i++) Wl[kk+16*h][cq+i]=src[i];
      }
    }
    __syncthreads();
    #pragma unroll
    for(int k=0;k<32;k++){
      float sv[4], wv[4];
      #pragma unroll
      for(int i=0;i<4;i++) sv[i]=Sl[ty*4+i][k];
      #pragma unroll
      for(int i=0;i<4;i++) wv[i]=Wl[k][tx+32*i];
      #pragma unroll
      for(int a=0;a<4;a++)
        #pragma unroll
        for(int b2=0;b2<4;b2++) acc[a][b2]+=sv[a]*wv[b2];
    }
    __syncthreads();
  }
  #pragma unroll
  for(int a=0;a<4;a++)
    #pragma unroll
    for(int b2=0;b2<4;b2++){
      int r=r0+ty*4+a, col=tx+32*b2;
      out[(size_t)r*128+col]=fmaxf(acc[a][b2],0.f);
    }
}

// ---------------- host ----------------
extern "C" void kernel_launch(void* const* d_in, const int* in_sizes, int n_in,
                              void* d_out, int out_size, void* d_ws, size_t ws_size,
                              hipStream_t stream){
  const float* z0 =(const float*)d_in[0];
  const float* z1 =(const float*)d_in[1];
  const float* z2 =(const float*)d_in[2];
  const float* L0 =(const float*)d_in[3];
  const float* L1d=(const float*)d_in[4];
  const float* L1u=(const float*)d_in[5];
  const float* L2 =(const float*)d_in[6];
  const float* B1 =(const float*)d_in[7];
  const float* B2 =(const float*)d_in[8];
  const float* Wd =(const float*)d_in[9];
  const float* Wu =(const float*)d_in[10];
  const float* Wh =(const float*)d_in[11];
  const float* Wb1=(const float*)d_in[12];
  const float* Wb2=(const float*)d_in[13];
  const float* adw=(const float*)d_in[14];
  const float* adb=(const float*)d_in[15];
  const float* auw=(const float*)d_in[16];
  const float* aub=(const float*)d_in[17];
  float* ws=(float*)d_ws;
  int* wsi=(int*)d_ws;
  float* out=(float*)d_out;

  hipLaunchKernelGGL(k_wprep, dim3(64), dim3(256), 0, stream, Wd,Wu,Wh,Wb1,Wb2,ws);
  hipLaunchKernelGGL(k_count, dim3(3328), dim3(256), 0, stream, L0,L1d,L1u,L2,B1,B2, wsi+W_CNT);
  hipLaunchKernelGGL(k_prefix, dim3(6), dim3(256), 0, stream, wsi+W_CNT, wsi+W_PTR);
  hipLaunchKernelGGL(k_fill, dim3(3328), dim3(256), 0, stream, L0,L1d,L1u,L2,B1,B2, wsi+W_PTR, wsi+W_CIDX, ws+W_VAL);
  hipLaunchKernelGGL(k_init, dim3(1024), dim3(256), 0, stream, ws);
  for (int j=0;j<M_LZ;j++){
    hipLaunchKernelGGL(k_lz_mv, dim3(1536), dim3(256), 0, stream, ws, j);
    hipLaunchKernelGGL(k_lz_up, dim3(24), dim3(256), 0, stream, ws, j);
  }
  hipLaunchKernelGGL(k_eig, dim3(1), dim3(256), 0, stream, ws);
  hipLaunchKernelGGL(k_attn_uv, dim3(768), dim3(256), 0, stream, z1, adw, auw, ws);
  for (int s=0;s<16;s++)
    hipLaunchKernelGGL(k_harm, dim3(1536), dim3(256), 0, stream, ws, z0,z1,z2, s);
  hipLaunchKernelGGL(k_spmm_fwd, dim3(3328), dim3(256), 0, stream, ws, z0,z1,z2, adb, aub);
  hipLaunchKernelGGL(k_spmm_scatter, dim3(1024), dim3(256), 0, stream, ws, z0, z1);
  hipLaunchKernelGGL(k_gemm, dim3(32), dim3(256), 0, stream, ws+W_SCAT+S0_OFF, ws+W_WCAT+WC0, out,          1024, 384);
  hipLaunchKernelGGL(k_gemm, dim3(96), dim3(256), 0, stream, ws+W_SCAT+S1_OFF, ws+W_WCAT+WC1, out+131072,   3072, 640);
  hipLaunchKernelGGL(k_gemm, dim3(64), dim3(256), 0, stream, ws+W_SCAT+S2_OFF, ws+W_WCAT+WC2, out+524288,   2048, 384);
}

// Round 3
// 3553.953 us; speedup vs baseline: 2.2755x; 1.0856x over previous
//
#include <hip/hip_runtime.h>

// ---------------- problem constants ----------------
constexpr int M_LZ = 96;           // Lanczos steps

// CSR capacity per matrix (expected nnz * ~1.25)
constexpr int CAP_L0 = 26240, CAP_L1 = 118016, CAP_L2 = 52480, CAP_B1 = 39360, CAP_B2 = 78720;
constexpr int CB_L0 = 0;
constexpr int CB_L1D = CB_L0 + CAP_L0;
constexpr int CB_L1U = CB_L1D + CAP_L1;
constexpr int CB_L2  = CB_L1U + CAP_L1;
constexpr int CB_B1  = CB_L2 + CAP_L2;
constexpr int CB_B2  = CB_B1 + CAP_B1;
constexpr int CAP_TOT= CB_B2 + CAP_B2;   // 432832
constexpr int CB_B1T = CAP_TOT;
constexpr int CB_B2T = CB_B1T + CAP_B1;
constexpr int CAP_TOT2 = CB_B2T + CAP_B2; // 550912

// rowptr offsets (ints) within W_PTR region
constexpr int P_L0=0, P_L1D=1025, P_L1U=4098, P_L2=7171, P_B1=9220, P_B2=10245;
constexpr int P_B1T=13320, P_B2T=16393;   // region size 18444
// row-count offsets within W_CNT region
constexpr int C_L0=0, C_L1D=1024, C_L1U=4096, C_L2=7168, C_B1=9216, C_B2=10240;
constexpr int C_B1T=13312, C_B2T=16384;   // region size 18432

// workspace layout (units: 4-byte words)
constexpr size_t W_CNT = 0;                         // 18432 ints
constexpr size_t W_PTR = 18432;                     // 18444 ints
constexpr size_t W_CUR = W_PTR + 18444;             // 5120 ints (B1T cursor @0, B2T @3072)
constexpr size_t W_CIDX= W_CUR + 5120;              // CAP_TOT2 ints
constexpr size_t W_VAL = W_CIDX + CAP_TOT2;         // CAP_TOT2 floats
constexpr size_t W_V   = W_VAL + CAP_TOT2;          // 5 slots * 6144 (v0,v1,v2, w0,w1)
constexpr size_t W_ACC = W_V + 5*6144;              // M_LZ*96 (bucketed dot accumulators)
constexpr size_t W_EPS = W_ACC + (size_t)M_LZ*96;   // 4
constexpr size_t W_UV  = W_EPS + 4;                 // 4*3072 (U_d,V_d,U_u,V_u)
constexpr size_t HBUF  = (size_t)6144*128;
constexpr size_t W_H   = W_UV + 4*3072;             // 2 ping-pong harmonic buffers
constexpr size_t W_SCAT= W_H + 2*HBUF;
constexpr size_t S0_OFF= 0;                          // 1024 x 384
constexpr size_t S1_OFF= (size_t)1024*384;           // 3072 x 640
constexpr size_t S2_OFF= S1_OFF + (size_t)3072*640;  // 2048 x 384
constexpr size_t SCAT_TOT = S2_OFF + (size_t)2048*384;
constexpr size_t W_WCAT= W_SCAT + SCAT_TOT;          // 1408*128 concatenated weights
constexpr size_t WC0=0, WC1=(size_t)384*128, WC2=WC1+(size_t)640*128;

__device__ __forceinline__ float wredf(float v){
  #pragma unroll
  for(int o=32;o;o>>=1) v += __shfl_xor(v,o,64);
  return v;
}
__device__ __forceinline__ int wredi(int v){
  #pragma unroll
  for(int o=32;o;o>>=1) v += __shfl_xor(v,o,64);
  return v;
}

// ---------------- weight prep + zeroing of atomic counters/accumulators ----------------
__global__ void k_wprep(const float* Wd,const float* Wu,const float* Wh,
                        const float* Wb1,const float* Wb2, float* ws){
  int t = blockIdx.x*256 + threadIdx.x;
  if (t >= 16384) return;
  int* wsi = (int*)ws;
  if (t < 5120) wsi[W_CNT + 13312 + t] = 0;          // transpose col counters
  if (t < (int)(M_LZ*96)) ws[W_ACC + t] = 0.f;       // lanczos dot buckets
  float sd = Wd[t]  + Wd[16384+t]  + Wd[32768+t];
  float su = Wu[t]  + Wu[16384+t]  + Wu[32768+t];
  float s1 = Wb1[t] + Wb1[16384+t] + Wb1[32768+t];
  float s2 = Wb2[t] + Wb2[16384+t] + Wb2[32768+t];
  float wh = Wh[t];
  float* W0 = ws + W_WCAT + WC0;
  float* W1 = ws + W_WCAT + WC1;
  float* W2 = ws + W_WCAT + WC2;
  W0[t]=sd; W0[16384+t]=s1; W0[32768+t]=wh;                       // [Wd;Wb1;Wh]
  W1[t]=sd; W1[16384+t]=su; W1[32768+t]=s1; W1[49152+t]=s2; W1[65536+t]=wh; // [Wd;Wu;Wb1;Wb2;Wh]
  W2[t]=su; W2[16384+t]=s2; W2[32768+t]=wh;                       // [Wu;Wb2;Wh]
}

// ---------------- CSR extraction ----------------
__device__ __forceinline__ void mat_meta(int wid, const float* L0,const float* L1d,const float* L1u,
    const float* L2,const float* B1,const float* B2,
    const float*& M,int& ncol,int& lrow,int& co,int& po,int& cb,int& cap,int& tco){
  if (wid < 1024){ M=L0;  ncol=1024; lrow=wid;        co=C_L0;  po=P_L0;  cb=CB_L0;  cap=CAP_L0; tco=-1; }
  else if (wid < 4096){ M=L1d; ncol=3072; lrow=wid-1024;  co=C_L1D; po=P_L1D; cb=CB_L1D; cap=CAP_L1; tco=-1; }
  else if (wid < 7168){ M=L1u; ncol=3072; lrow=wid-4096;  co=C_L1U; po=P_L1U; cb=CB_L1U; cap=CAP_L1; tco=-1; }
  else if (wid < 9216){ M=L2;  ncol=2048; lrow=wid-7168;  co=C_L2;  po=P_L2;  cb=CB_L2;  cap=CAP_L2; tco=-1; }
  else if (wid < 10240){ M=B1; ncol=3072; lrow=wid-9216;  co=C_B1;  po=P_B1;  cb=CB_B1;  cap=CAP_B1; tco=C_B1T; }
  else { M=B2; ncol=2048; lrow=wid-10240; co=C_B2;  po=P_B2;  cb=CB_B2;  cap=CAP_B2; tco=C_B2T; }
}

__global__ void k_count(const float* L0,const float* L1d,const float* L1u,const float* L2,
                        const float* B1,const float* B2,int* cnt){
  int wid = blockIdx.x*4 + (threadIdx.x>>6);
  int lane = threadIdx.x & 63;
  if (wid >= 13312) return;
  const float* M; int ncol,lrow,co,po,cb,cap,tco;
  mat_meta(wid,L0,L1d,L1u,L2,B1,B2,M,ncol,lrow,co,po,cb,cap,tco);
  const float* row = M + (size_t)lrow*ncol;
  int c = 0;
  for (int j=lane; j<ncol; j+=64){
    bool nz = (row[j]!=0.0f);
    c += nz;
    if (nz && tco>=0) atomicAdd(cnt + tco + j, 1);   // transpose column counts
  }
  c = wredi(c);
  if (lane==0) cnt[co+lrow] = c;
}

__global__ void k_prefix(const int* cnt, int* ptr, int* cur){
  __shared__ int lds[257];
  const int rows[8]={1024,3072,3072,2048,1024,3072,3072,2048};
  const int cofs[8]={C_L0,C_L1D,C_L1U,C_L2,C_B1,C_B2,C_B1T,C_B2T};
  const int pofs[8]={P_L0,P_L1D,P_L1U,P_L2,P_B1,P_B2,P_B1T,P_B2T};
  int b=blockIdx.x, t=threadIdx.x;
  int R=rows[b]; const int* c=cnt+cofs[b]; int* p=ptr+pofs[b];
  int* cc = (b==6)? cur : (b==7)? cur+3072 : nullptr;
  int chunk=(R+255)/256;
  int lo=t*chunk, hi=min(R,lo+chunk);
  int s=0;
  for(int i=lo;i<hi;i++) s+=c[i];
  lds[t]=s; __syncthreads();
  if(t==0){ int run=0; for(int i=0;i<256;i++){int x=lds[i];lds[i]=run;run+=x;} lds[256]=run; }
  __syncthreads();
  int run=lds[t];
  for(int i=lo;i<hi;i++){ p[i]=run; if(cc) cc[i]=run; run+=c[i]; }
  if(t==0) p[R]=lds[256];
}

__global__ void k_fill(const float* L0,const float* L1d,const float* L1u,const float* L2,
                       const float* B1,const float* B2,const int* ptr,int* cidx,float* val){
  int wid = blockIdx.x*4 + (threadIdx.x>>6);
  int lane = threadIdx.x & 63;
  if (wid >= 13312) return;
  const float* M; int ncol,lrow,co,po,cb,cap,tco;
  mat_meta(wid,L0,L1d,L1u,L2,B1,B2,M,ncol,lrow,co,po,cb,cap,tco);
  const float* row = M + (size_t)lrow*ncol;
  int base = ptr[po+lrow];
  int run = 0;
  for (int j0=0; j0<ncol; j0+=64){
    int j = j0 + lane;
    float v = (j<ncol)? row[j] : 0.0f;
    unsigned long long m = __ballot(v!=0.0f);
    if (v!=0.0f){
      int pos = base + run + __popcll(m & ((1ull<<lane)-1ull));
      if (pos < cap){ cidx[cb+pos]=j; val[cb+pos]=v; }
    }
    run += __popcll(m);
  }
}

// ---------------- CSR -> CSC (CSR of B1^T, B2^T) via cursor atomics ----------------
__global__ void k_fillT(float* ws){
  int wid = blockIdx.x*4 + (threadIdx.x>>6);
  int lane = threadIdx.x & 63;
  if (wid >= 4096) return;
  int* wsi=(int*)ws;
  const int* ptr=wsi+W_PTR; int* cidx=wsi+W_CIDX; float* val=ws+W_VAL;
  int* cur=wsi+W_CUR;
  if (wid < 1024){           // B1 rows -> B1T
    int r=wid;
    int e=ptr[P_B1+r+1];
    for(int k=ptr[P_B1+r]+lane;k<e;k+=64){
      int c=cidx[CB_B1+k]; float v=val[CB_B1+k];
      int pos=atomicAdd(cur+c,1);
      cidx[CB_B1T+pos]=r; val[CB_B1T+pos]=v;
    }
  } else {                   // B2 rows -> B2T
    int r=wid-1024;
    int e=ptr[P_B2+r+1];
    for(int k=ptr[P_B2+r]+lane;k<e;k+=64){
      int c=cidx[CB_B2+k]; float v=val[CB_B2+k];
      int pos=atomicAdd(cur+3072+c,1);
      cidx[CB_B2T+pos]=r; val[CB_B2T+pos]=v;
    }
  }
}

// ---------------- init: v0 + zero v-slots 1,2 ----------------
__global__ void k_init(float* ws){
  int i = blockIdx.x*256 + threadIdx.x;   // 72 blocks * 256 = 18432
  if (i < 6144){
    float invs;
    if (i<1024) invs = 0.03125f;             // 1/sqrt(1024)
    else if (i<4096) invs = 0.0180421959f;   // 1/sqrt(3072)
    else invs = 0.0220970869f;               // 1/sqrt(2048)
    unsigned u = (unsigned)i*2654435761u; u^=u>>16; u*=2246822519u; u^=u>>13;
    ws[W_V + i] = (u&1)? invs : -invs;       // v0 (slot 0)
  } else {
    ws[W_V + i] = 0.f;                       // v-slots 1,2 = 0
  }
}

// ---------------- merged Lanczos step j: reconstruct v_j, w_j = A v_j, dots ----------
// v_j -> slot j%3 ; w_j -> slot 3+(j&1). One wave per row; 1536 blocks x 256.
__global__ __launch_bounds__(256) void k_lz(float* ws, int j){
  int wid = blockIdx.x*4 + (threadIdx.x>>6);
  int lane = threadIdx.x & 63;
  int c, p, nbase;
  if (wid<1024){ c=0; p=wid;      nbase=0; }
  else if (wid<4096){ c=1; p=wid-1024; nbase=1024; }
  else { c=2; p=wid-4096; nbase=4096; }
  __shared__ float sc[3];
  __shared__ float red[3][4];
  if (threadIdx.x==0){
    if (j==0){ sc[0]=0.f; sc[1]=0.f; sc[2]=1.f; }
    else {
      const float* A = ws + W_ACC + (size_t)(j-1)*96 + c*24;
      float a=0.f,g=0.f,n=0.f;
      #pragma unroll
      for(int b=0;b<8;b++){ a+=A[b]; g+=A[8+b]; n+=A[16+b]; }
      float beta = sqrtf(fmaxf(n - a*a - g*g, 1e-20f));
      sc[0]=a; sc[1]=g; sc[2]=1.f/beta;
    }
  }
  __syncthreads();
  float a=sc[0], g=sc[1], ib=sc[2];
  float* vcur       = ws + W_V + (size_t)(j%3)*6144 + nbase;        // v_j (write unless j==0)
  const float* vm1  = ws + W_V + (size_t)((j+2)%3)*6144 + nbase;    // v_{j-1}
  const float* vm2  = ws + W_V + (size_t)((j+1)%3)*6144 + nbase;    // v_{j-2}
  const float* wprev= ws + W_V + (size_t)(3 + ((j+1)&1))*6144 + nbase; // w_{j-1}
  float* wcur       = ws + W_V + (size_t)(3 + (j&1))*6144 + nbase;     // w_j
  const int* wsi = (const int*)ws;
  const int* ptr = wsi + W_PTR;
  const int* cidx= wsi + W_CIDX;
  const float* val = ws + W_VAL;
  float wp = 0.f;
  #define GATHER(PP,CBB) { \
    const int* rp = ptr + PP; int e=rp[p+1]; \
    for (int k=rp[p]+lane; k<e; k+=64){ \
      int q = cidx[CBB+k]; float v = val[CBB+k]; \
      float vq = (j==0)? vcur[q] : (wprev[q] - a*vm1[q] - g*vm2[q])*ib; \
      wp += v*vq; \
    } }
  if (c==0){ GATHER(P_L0, CB_L0) }
  else if (c==1){ GATHER(P_L1D, CB_L1D) GATHER(P_L1U, CB_L1U) }
  else { GATHER(P_L2, CB_L2) }
  #undef GATHER
  wp = wredf(wp);
  int wv = threadIdx.x>>6;
  if (lane==0){
    float vp;
    if (j==0) vp = vcur[p];
    else { vp = (wprev[p] - a*vm1[p] - g*vm2[p])*ib; vcur[p] = vp; }
    wcur[p] = wp;
    red[0][wv] = vp*wp;
    red[1][wv] = vm1[p]*wp;
    red[2][wv] = wp*wp;
  }
  __syncthreads();
  if (threadIdx.x==0){
    float A = red[0][0]+red[0][1]+red[0][2]+red[0][3];
    float G = red[1][0]+red[1][1]+red[1][2]+red[1][3];
    float Nn= red[2][0]+red[2][1]+red[2][2]+red[2][3];
    int bucket = blockIdx.x & 7;
    float* acc = ws + W_ACC + (size_t)j*96 + (size_t)c*24;
    atomicAdd(acc + 0*8 + bucket, A);
    atomicAdd(acc + 1*8 + bucket, G);
    atomicAdd(acc + 2*8 + bucket, Nn);
  }
}

// ---------------- largest Ritz value via wave-parallel Sturm bisection ----------------
__global__ void k_eig(float* ws){
  __shared__ float TAs[3][M_LZ], TBs[3][M_LZ];
  int c = threadIdx.x>>6, lane = threadIdx.x&63;
  if (c<3){
    for (int i=lane;i<M_LZ;i+=64){
      const float* A = ws + W_ACC + (size_t)i*96 + (size_t)c*24;
      float a=0.f,g=0.f,n=0.f;
      #pragma unroll
      for(int b=0;b<8;b++){ a+=A[b]; g+=A[8+b]; n+=A[16+b]; }
      TAs[c][i]=a;
      TBs[c][i]=sqrtf(fmaxf(n - a*a - g*g, 1e-20f));
    }
  }
  __syncthreads();
  if (c>=3) return;
  const float* TA = TAs[c];
  const float* TB = TBs[c];
  double lo=1e300, hi=-1e300;
  for (int i=lane;i<M_LZ;i+=64){
    double r=(i? fabs((double)TB[i-1]):0.0) + (i<M_LZ-1? fabs((double)TB[i]):0.0);
    lo = fmin(lo,(double)TA[i]-r); hi = fmax(hi,(double)TA[i]+r);
  }
  #pragma unroll
  for(int o=32;o;o>>=1){ lo=fmin(lo,__shfl_xor(lo,o,64)); hi=fmax(hi,__shfl_xor(hi,o,64)); }
  lo -= 1.0; hi += 1.0;
  for (int round=0; round<4; round++){
    double x = lo + (hi-lo)*(double)(lane+1)/65.0;
    double d = 1.0; int cnt=0;
    for (int i=0;i<M_LZ;i++){
      double bi = i? (double)TB[i-1] : 0.0;
      d = ((double)TA[i]-x) - bi*bi/d;
      if (d==0.0) d = -1e-300;
      if (d<0.0) cnt++;
    }
    double nlo = (cnt< M_LZ)? x : -1e300;
    double nhi = (cnt==M_LZ)? x :  1e300;
    #pragma unroll
    for(int o=32;o;o>>=1){ nlo=fmax(nlo,__shfl_xor(nlo,o,64)); nhi=fmin(nhi,__shfl_xor(nhi,o,64)); }
    if (nlo>-1e299) lo=nlo;
    if (nhi< 1e299) hi=nhi;
  }
  double lam = 0.5*(lo+hi);
  if (lane==0) ws[W_EPS+c] = (lam>0.0)? (float)(1.0/lam) : 0.1f;
}

// ---------------- attention U,V vectors ----------------
__global__ void k_attn_uv(const float* z1, const float* wd, const float* wu, float* ws){
  int wid = blockIdx.x*4 + (threadIdx.x>>6);
  int lane = threadIdx.x & 63;
  if (wid>=3072) return;
  float2 x = ((const float2*)(z1 + (size_t)wid*128))[lane];
  float2 a0 = ((const float2*)wd)[lane];      // w[0:128]
  float2 a1 = ((const float2*)wd)[64+lane];   // w[128:256]
  float2 b0 = ((const float2*)wu)[lane];
  float2 b1 = ((const float2*)wu)[64+lane];
  float ud = x.x*a0.x + x.y*a0.y;
  float vd = x.x*a1.x + x.y*a1.y;
  float uu = x.x*b0.x + x.y*b0.y;
  float vu = x.x*b1.x + x.y*b1.y;
  ud=wredf(ud); vd=wredf(vd); uu=wredf(uu); vu=wredf(vu);
  if (lane==0){
    ws[W_UV+wid]=ud; ws[W_UV+3072+wid]=vd;
    ws[W_UV+6144+wid]=uu; ws[W_UV+9216+wid]=vu;
  }
}

// ---------------- harmonic step: y <- y - eps*(L y); one WAVE per row --------------
__global__ __launch_bounds__(256) void k_harm(float* ws, const float* z0,const float* z1,const float* z2,int step){
  int wid = blockIdx.x*4 + (threadIdx.x>>6);
  int lane = threadIdx.x & 63;
  int c, p;
  if (wid<1024){ c=0; p=wid; }
  else if (wid<4096){ c=1; p=wid-1024; }
  else { c=2; p=wid-4096; }
  const float* z = (c==0)?z0:(c==1)?z1:z2;
  float eps = ws[W_EPS+c];
  size_t cb = (c==0)? 0 : (c==1)? (size_t)1024*128 : (size_t)4096*128;
  const float* in = (step==0)? z : ws + W_H + (size_t)((step-1)&1)*HBUF + cb;
  float* out; size_t ostride;
  if (step<15){ out = ws + W_H + (size_t)(step&1)*HBUF + cb; ostride=128; }
  else {
    if(c==0){ out=ws+W_SCAT+S0_OFF+256; ostride=384; }
    else if(c==1){ out=ws+W_SCAT+S1_OFF+512; ostride=640; }
    else { out=ws+W_SCAT+S2_OFF+256; ostride=384; }
  }
  const int* wsi=(const int*)ws;
  const int* ptr=wsi+W_PTR; const int* cidx=wsi+W_CIDX; const float* val=ws+W_VAL;
  float2 acc = ((const float2*)(in + (size_t)p*128))[lane];
  float2 s = {0.f,0.f};
  #define HGATHER(PP,CBB) { \
    const int* rp=ptr+PP; int e=rp[p+1]; \
    for(int k=rp[p];k<e;k++){ \
      float v=val[CBB+k]; int q=cidx[CBB+k]; \
      float2 xq=((const float2*)(in+(size_t)q*128))[lane]; \
      s.x+=v*xq.x; s.y+=v*xq.y; \
    } }
  if (c==0){ HGATHER(P_L0, CB_L0) }
  else if (c==1){ HGATHER(P_L1D, CB_L1D) HGATHER(P_L1U, CB_L1U) }
  else { HGATHER(P_L2, CB_L2) }
  #undef HGATHER
  acc.x -= eps*s.x; acc.y -= eps*s.y;
  ((float2*)(out + (size_t)p*ostride))[lane] = acc;
}

// ---------------- forward SpMMs into staging (incl. attention + transposes) --------
__global__ void k_spmm_fwd(float* ws, const float* z0,const float* z1,const float* z2,
                           const float* bd, const float* bu){
  int wid = blockIdx.x*4 + (threadIdx.x>>6);
  int lane = threadIdx.x & 63;
  if (wid>=18432) return;
  int task, p;
  if(wid<1024){task=0;p=wid;}
  else if(wid<2048){task=1;p=wid-1024;}
  else if(wid<5120){task=2;p=wid-2048;}
  else if(wid<8192){task=3;p=wid-5120;}
  else if(wid<11264){task=4;p=wid-8192;}
  else if(wid<13312){task=5;p=wid-11264;}
  else if(wid<16384){task=6;p=wid-13312;}
  else {task=7;p=wid-16384;}
  const int* wsi=(const int*)ws;
  const int* ptr=wsi+W_PTR; const int* cidx=wsi+W_CIDX; const float* val=ws+W_VAL;
  const float* in; const int* rp; int cb; float* out; int ostride;
  int mode=0; float Vp=0.f, bb=0.f; const float* U=nullptr;
  switch(task){
    case 0: rp=ptr+P_L0;  cb=CB_L0;  in=z0; out=ws+W_SCAT+S0_OFF+0;   ostride=384; break;
    case 1: rp=ptr+P_B1;  cb=CB_B1;  in=z1; out=ws+W_SCAT+S0_OFF+128; ostride=384; break;
    case 2: rp=ptr+P_L1D; cb=CB_L1D; in=z1; out=ws+W_SCAT+S1_OFF+0;   ostride=640;
            mode=1; U=ws+W_UV; Vp=ws[W_UV+3072+p]; bb=bd[0]; break;
    case 3: rp=ptr+P_L1U; cb=CB_L1U; in=z1; out=ws+W_SCAT+S1_OFF+128; ostride=640;
            mode=1; U=ws+W_UV+6144; Vp=ws[W_UV+9216+p]; bb=bu[0]; break;
    case 4: rp=ptr+P_B2;  cb=CB_B2;  in=z2; out=ws+W_SCAT+S1_OFF+384; ostride=640; break;
    case 5: rp=ptr+P_L2;  cb=CB_L2;  in=z2; out=ws+W_SCAT+S2_OFF+0;   ostride=384; break;
    case 6: rp=ptr+P_B1T; cb=CB_B1T; in=z0; out=ws+W_SCAT+S1_OFF+256; ostride=640; break;
    default:rp=ptr+P_B2T; cb=CB_B2T; in=z1; out=ws+W_SCAT+S2_OFF+128; ostride=384; break;
  }
  float2 s={0.f,0.f};
  int e=rp[p+1];
  for (int k=rp[p]; k<e; k++){
    int q = cidx[cb+k];
    float v;
    if (mode) v = 1.0f/(1.0f+__expf(-(U[q]+Vp+bb)));   // A[p,q] = sigma(U_q + V_p + b)
    else v = val[cb+k];
    float2 xq = ((const float2*)(in+(size_t)q*128))[lane];
    s.x += v*xq.x; s.y += v*xq.y;
  }
  ((float2*)(out + (size_t)p*ostride))[lane] = s;
}

// ---------------- projection GEMM: out = relu(S @ Wcat), N=128 ----------------
__global__ __launch_bounds__(256) void k_gemm(const float* S, const float* W, float* out, int M, int K){
  __shared__ float Sl[32][33];
  __shared__ float Wl[32][128];
  int t=threadIdx.x;
  int r0=blockIdx.x*32;
  int ty=t>>5, tx=t&31;
  float acc[4][4]={};
  for (int k0=0; k0<K; k0+=32){
    {
      int r=t>>3, kq=(t&7)*4;
      const float* src=S+(size_t)(r0+r)*K + k0+kq;
      Sl[r][kq]=src[0]; Sl[r][kq+1]=src[1]; Sl[r][kq+2]=src[2]; Sl[r][kq+3]=src[3];
    }
    {
      int kk=t>>4, cq=(t&15)*8;
      #pragma unroll
      for(int h=0;h<2;h++){
        const float* src=W+(size_t)(k0+kk+16*h)*128+cq;
        #pragma unroll
        for(int i=0;i<8;i++) Wl[kk+16*h][cq+i]=src[i];
      }
    }
    __syncthreads();
    #pragma unroll
    for(int k=0;k<32;k++){
      float sv[4], wv[4];
      #pragma unroll
      for(int i=0;i<4;i++) sv[i]=Sl[ty*4+i][k];
      #pragma unroll
      for(int i=0;i<4;i++) wv[i]=Wl[k][tx+32*i];
      #pragma unroll
      for(int a=0;a<4;a++)
        #pragma unroll
        for(int b2=0;b2<4;b2++) acc[a][b2]+=sv[a]*wv[b2];
    }
    __syncthreads();
  }
  #pragma unroll
  for(int a=0;a<4;a++)
    #pragma unroll
    for(int b2=0;b2<4;b2++){
      int r=r0+ty*4+a, col=tx+32*b2;
      out[(size_t)r*128+col]=fmaxf(acc[a][b2],0.f);
    }
}

// ---------------- host ----------------
extern "C" void kernel_launch(void* const* d_in, const int* in_sizes, int n_in,
                              void* d_out, int out_size, void* d_ws, size_t ws_size,
                              hipStream_t stream){
  const float* z0 =(const float*)d_in[0];
  const float* z1 =(const float*)d_in[1];
  const float* z2 =(const float*)d_in[2];
  const float* L0 =(const float*)d_in[3];
  const float* L1d=(const float*)d_in[4];
  const float* L1u=(const float*)d_in[5];
  const float* L2 =(const float*)d_in[6];
  const float* B1 =(const float*)d_in[7];
  const float* B2 =(const float*)d_in[8];
  const float* Wd =(const float*)d_in[9];
  const float* Wu =(const float*)d_in[10];
  const float* Wh =(const float*)d_in[11];
  const float* Wb1=(const float*)d_in[12];
  const float* Wb2=(const float*)d_in[13];
  const float* adw=(const float*)d_in[14];
  const float* adb=(const float*)d_in[15];
  const float* auw=(const float*)d_in[16];
  const float* aub=(const float*)d_in[17];
  float* ws=(float*)d_ws;
  int* wsi=(int*)d_ws;
  float* out=(float*)d_out;

  hipLaunchKernelGGL(k_wprep, dim3(64), dim3(256), 0, stream, Wd,Wu,Wh,Wb1,Wb2,ws);
  hipLaunchKernelGGL(k_count, dim3(3328), dim3(256), 0, stream, L0,L1d,L1u,L2,B1,B2, wsi+W_CNT);
  hipLaunchKernelGGL(k_prefix, dim3(8), dim3(256), 0, stream, wsi+W_CNT, wsi+W_PTR, wsi+W_CUR);
  hipLaunchKernelGGL(k_fill, dim3(3328), dim3(256), 0, stream, L0,L1d,L1u,L2,B1,B2, wsi+W_PTR, wsi+W_CIDX, ws+W_VAL);
  hipLaunchKernelGGL(k_fillT, dim3(1024), dim3(256), 0, stream, ws);
  hipLaunchKernelGGL(k_init, dim3(72), dim3(256), 0, stream, ws);
  for (int j=0;j<M_LZ;j++)
    hipLaunchKernelGGL(k_lz, dim3(1536), dim3(256), 0, stream, ws, j);
  hipLaunchKernelGGL(k_eig, dim3(1), dim3(256), 0, stream, ws);
  hipLaunchKernelGGL(k_attn_uv, dim3(768), dim3(256), 0, stream, z1, adw, auw, ws);
  for (int s=0;s<16;s++)
    hipLaunchKernelGGL(k_harm, dim3(1536), dim3(256), 0, stream, ws, z0,z1,z2, s);
  hipLaunchKernelGGL(k_spmm_fwd, dim3(4608), dim3(256), 0, stream, ws, z0,z1,z2, adb, aub);
  hipLaunchKernelGGL(k_gemm, dim3(32), dim3(256), 0, stream, ws+W_SCAT+S0_OFF, ws+W_WCAT+WC0, out,          1024, 384);
  hipLaunchKernelGGL(k_gemm, dim3(96), dim3(256), 0, stream, ws+W_SCAT+S1_OFF, ws+W_WCAT+WC1, out+131072,   3072, 640);
  hipLaunchKernelGGL(k_gemm, dim3(64), dim3(256), 0, stream, ws+W_SCAT+S2_OFF, ws+W_WCAT+WC2, out+524288,   2048, 384);
}